// Round 3
// baseline (221.025 us; speedup 1.0000x reference)
//
#include <hip/hip_runtime.h>
#include <math.h>

// out[n,0,i,j] = (1/64) * sum_{c,p,q} w[c]*sqrt(z[n,c,p,q]) * sqrt(x[n,c,i+p,j+q])
//   N=16, C=256, k=8, m=63, mo=56.
//
// Fused shift-GEMM, round 3: round 2 was latency-bound (all pipes idle: HBM 8%,
// VALU 20%, MFMA 1.5%, occupancy 20%). Changes:
//   - CSPLIT 4->8: grid 1024 blocks -> 4 blocks/CU -> 16 waves/CU (50% occ cap)
//   - explicit prefetch pipeline: next group's 8 gather loads issued before the
//     current group's sqrt/cvt/MFMA/scatter (overlaps ~200-900 cy load latency)
//   - v_cvt_pk_bf16_f32 for B-frag packing; scatter validity hoisted per-iter

#define NS 16
#define NC 256
#define PQ 64
#define MI 63
#define MO 56
#define NPIX (MI*MI)            // 3969
#define NOUT (MO*MO)            // 3136

#define IH 7                    // output rows per band
#define NBAND 8                 // 8*7 = 56 output rows
#define CSPLIT 8                // channel chunks
#define NCH (NC/CSPLIT)         // 32 channels per block -> single K-step
#define TROWS (IH + 7)          // 14 pixel rows per tile
#define TPIX (TROWS*MI)         // 882 pixels per tile (contiguous in memory)
#define NGRP ((TPIX + 15)/16)   // 56 pixel groups -> 14 per wave
#define ZP (NCH + 8)            // zs row stride (shorts)

typedef __attribute__((ext_vector_type(8))) short bf16x8;
typedef __attribute__((ext_vector_type(4))) float f32x4;

static __device__ __forceinline__ short f2bf(float f) {
    union { float f; unsigned u; } v; v.f = f;
    return (short)((v.u + 0x7fffu + ((v.u >> 16) & 1u)) >> 16);
}

__global__ __launch_bounds__(256, 4)
void bhat_fused(const float* __restrict__ z, const float* __restrict__ x,
                const float* __restrict__ w, float* __restrict__ out) {
    __shared__ short zs[PQ * ZP];       // A = w*sqrt(z): zs[pq][c], 5.1 KB bf16
    __shared__ float oacc[IH * MO];     // band output accumulator, 1.57 KB

    const int n    = blockIdx.x;
    const int band = blockIdx.y;
    const int c0   = blockIdx.z * NCH;
    const int tid  = threadIdx.x;
    const int i0   = band * IH;

    for (int i = tid; i < IH * MO; i += 256) oacc[i] = 0.0f;

    // Stage A chunk: coalesced z reads (idx = c*64+pq), wave-uniform w[c].
    {
        const float* zb = z + ((size_t)n * NC + c0) * PQ;
        #pragma unroll
        for (int it = 0; it < (PQ * NCH) / 256; ++it) {
            int idx = it * 256 + tid;
            int c = idx >> 6, pq = idx & 63;
            zs[pq * ZP + c] = f2bf(w[c0 + c] * sqrtf(zb[(size_t)c * PQ + pq]));
        }
    }
    __syncthreads();

    const int wave = tid >> 6, lane = tid & 63;
    const int lm = lane & 15, lg = lane >> 4;
    const int cb = lg * 8;              // this lane-group's channel base

    // Scatter constants: element (mt,t) is pq = mt*16 + lg*4 + t -> p = mt*2+pv[t], q = qv[t]
    int pv[4], qv[4];
    #pragma unroll
    for (int t = 0; t < 4; ++t) { int e = lg * 4 + t; pv[t] = e >> 3; qv[t] = e & 7; }

    // Band's pixel tile = rows i0..i0+13, all 63 cols (contiguous flat range).
    const float* xb = x + ((size_t)n * NC + c0) * NPIX + (size_t)i0 * MI;

    // Pipeline prologue: load group g = wave.
    float xv[8];
    {
        int pit = wave * 16 + lm; if (pit > TPIX - 1) pit = TPIX - 1;
        #pragma unroll
        for (int j = 0; j < 8; ++j) xv[j] = xb[(size_t)(cb + j) * NPIX + pit];
    }

    for (int g = wave; g < NGRP; g += 4) {
        const int pit = g * 16 + lm;

        // Prefetch next group's gathers (covered by this group's compute).
        float xn[8];
        const int gn = g + 4;
        if (gn < NGRP) {
            int pn = gn * 16 + lm; if (pn > TPIX - 1) pn = TPIX - 1;
            #pragma unroll
            for (int j = 0; j < 8; ++j) xn[j] = xb[(size_t)(cb + j) * NPIX + pn];
        }

        // B-frag: sqrt + packed bf16 convert (4x v_cvt_pk_bf16_f32).
        union { bf16x8 v; unsigned u[4]; } bf;
        #pragma unroll
        for (int j = 0; j < 4; ++j) {
            float s0 = sqrtf(xv[2 * j]);
            float s1 = sqrtf(xv[2 * j + 1]);
            asm("v_cvt_pk_bf16_f32 %0, %1, %2" : "=v"(bf.u[j]) : "v"(s0), "v"(s1));
        }

        // Single K-step (32 channels): A/B use the same intra-lane k-order, so any
        // HW k-permutation cancels. D layout (m89): pq = mt*16+lg*4+t, pixel = lm.
        f32x4 acc[4];
        #pragma unroll
        for (int mt = 0; mt < 4; ++mt) {
            const bf16x8 af = *(const bf16x8*)(&zs[(mt * 16 + lm) * ZP + cb]);
            acc[mt] = __builtin_amdgcn_mfma_f32_16x16x32_bf16(
                af, bf.v, (f32x4){0.f, 0.f, 0.f, 0.f}, 0, 0, 0);
        }

        // Scatter into band accumulator: S[pq][pit] -> oacc[rt-p][s-q].
        const int rt = pit / MI, s = pit - rt * MI;
        const bool pvd = pit < TPIX;
        int jj[4]; bool jv[4];
        #pragma unroll
        for (int t = 0; t < 4; ++t) { jj[t] = s - qv[t]; jv[t] = (unsigned)jj[t] < MO; }
        #pragma unroll
        for (int mt = 0; mt < 4; ++mt)
            #pragma unroll
            for (int t = 0; t < 4; ++t) {
                const int oi = rt - mt * 2 - pv[t];
                if (pvd && jv[t] && (unsigned)oi < IH)
                    atomicAdd(&oacc[oi * MO + jj[t]], acc[mt][t]);
            }

        #pragma unroll
        for (int j = 0; j < 8; ++j) xv[j] = xn[j];
    }

    __syncthreads();
    float* ob = out + (size_t)n * NOUT + (size_t)i0 * MO;
    for (int i = tid; i < IH * MO; i += 256)
        atomicAdd(&ob[i], oacc[i] * (1.0f / 64.0f));
}

extern "C" void kernel_launch(void* const* d_in, const int* in_sizes, int n_in,
                              void* d_out, int out_size, void* d_ws, size_t ws_size,
                              hipStream_t stream) {
    const float* z = (const float*)d_in[0];   // (16,256,8,8)
    const float* x = (const float*)d_in[1];   // (16,256,63,63)
    const float* w = (const float*)d_in[2];   // (1,256,1,1,1) -> 256 floats
    float* out = (float*)d_out;               // (16,1,56,56)

    // d_out is re-poisoned each iteration; chunk blocks accumulate atomically.
    hipMemsetAsync(out, 0, (size_t)out_size * sizeof(float), stream);

    dim3 grid(NS, NBAND, CSPLIT);             // (16, 8, 8) = 1024 blocks
    bhat_fused<<<grid, 256, 0, stream>>>(z, x, w, out);
}

// Round 4
// 149.558 us; speedup vs baseline: 1.4779x; 1.4779x over previous
//
#include <hip/hip_runtime.h>
#include <math.h>

// out[n,0,i,j] = (1/64) * sum_{c,p,q} w[c]*sqrt(z[n,c,p,q]) * sqrt(x[n,c,i+p,j+q])
//   N=16, C=256, k=8, m=63, mo=56.
//
// Round 4: rounds 2/3 showed the pq->output LDS-atomic scatter was ~55% of time
// (doubling it scaled time 92->143us). Eliminate it: fold the p-shift into the
// MFMA K-dim.  U[q][i][j] = sum_{c,p} Az[c][p*8+q] * sx[c][i+p][j]  with
// K=(c,p), M=q(16 rows, 8 used), N=j.  A is DENSE; the p-shift is just reading
// shifted rows of a register-cached x column; out[i][j] = (1/64) sum_q U[q][i][j+q]
// is 8 plain LDS reads per output, once per block. No atomics in the main loop.

#define NS 16
#define NC 256
#define MI 63
#define MO 56
#define NPIX (MI*MI)          // 3969
#define NOUT (MO*MO)          // 3136

#define IH 8                  // output rows per band
#define NBAND 7               // 7*8 = 56
#define CSPLIT 8              // channel chunks -> global atomic epilogue
#define NCH (NC/CSPLIT)       // 32 channels per block
#define G 8                   // channels per staging group
#define NG (NCH/G)            // 4 groups
#define XROWS (IH+7)          // 15 x-rows per band
#define XRW (G*XROWS*MI)      // fp32 words per xs buffer = 7560
#define ZROW 72               // zf padded row pitch (shorts), keeps b128 16B-aligned
#define UPITCH 66             // U row pitch (fp32)

typedef __attribute__((ext_vector_type(8))) short bf16x8;
typedef __attribute__((ext_vector_type(4))) float f32x4;

static __device__ __forceinline__ short f2bf(float f) {
    union { float f; unsigned u; } v; v.f = f;
    return (short)((v.u + 0x7fffu + ((v.u >> 16) & 1u)) >> 16);
}

__global__ __launch_bounds__(512, 2)
void bhat_u(const float* __restrict__ z, const float* __restrict__ x,
            const float* __restrict__ w, float* __restrict__ out) {
    __shared__ float xs[2 * XRW];            // 60480 B: double-buffered sqrt(x) tiles
    __shared__ short zf[NG * 8 * ZROW];      // 4608 B: A-frag-ready w*sqrt(z)
    float* U = xs;                           // q-slab aliases buf0 after the k-loop

    const int n    = blockIdx.x;
    const int band = blockIdx.y;
    const int c0   = blockIdx.z * NCH;
    const int tid  = threadIdx.x;
    const int i0   = band * IH;              // output row base; x rows i0..i0+14

    // ---- stage A: zf[(g*8+q)*ZROW + k] = w*sqrt(z[c(k)][p(k)*8+q]),
    //      k-order (within 32-k-step): c_local = (k&31)>>2, p = (k>>5)*4 + (k&3).
    for (int idx = tid; idx < NG * 8 * 64; idx += 512) {
        int g = idx >> 9, rem = idx & 511;
        int q = rem >> 6, k = rem & 63;
        int cl = (k & 31) >> 2;
        int p  = ((k >> 5) << 2) + (k & 3);
        int c  = c0 + g * G + cl;
        float v = w[c] * sqrtf(z[((size_t)n * NC + c) * 64 + p * 8 + q]);
        zf[(g * 8 + q) * ZROW + k] = f2bf(v);
    }

    // ---- staging: xs[buf][ (cl*XROWS + r)*MI + j ] = sqrt(x[c][i0+r][j]), coalesced.
    auto stage = [&](int g, int buf) {
        const float* xg = x + (size_t)(n * NC + c0 + g * G) * NPIX + (size_t)i0 * MI;
        float* dst = &xs[buf * XRW];
        for (int idx = tid; idx < XRW; idx += 512) {
            int cl = idx / (XROWS * MI);
            int rj = idx - cl * (XROWS * MI);
            dst[idx] = sqrtf(xg[(size_t)cl * NPIX + rj]);
        }
    };

    const int wave = tid >> 6, lane = tid & 63;
    const int wj = wave & 3, wh = wave >> 2;   // j-tile, row-half
    const int lm = lane & 15, lg = lane >> 4;
    const int jb = wj * 16;                    // B col base (0..48)
    const int rb = wh * 4;                     // first band row for this wave

    f32x4 acc[4];
    #pragma unroll
    for (int il = 0; il < 4; ++il) acc[il] = (f32x4){0.f, 0.f, 0.f, 0.f};

    stage(0, 0);
    __syncthreads();

    for (int g = 0; g < NG; ++g) {
        if (g + 1 < NG) stage(g + 1, (g + 1) & 1);

        const float* xb = &xs[(g & 1) * XRW];
        // Register-cache this lane's two x columns (c = lg*2, lg*2+1), rows rb..rb+10.
        float xr[2][11];
        #pragma unroll
        for (int ci = 0; ci < 2; ++ci)
            #pragma unroll
            for (int r = 0; r < 11; ++r)
                xr[ci][r] = xb[((lg * 2 + ci) * XROWS + rb + r) * MI + jb + lm];

        // A-frags: lane row q = lm&7 (rows 8-15 duplicate -> D rows 8-15 dup, unread).
        bf16x8 af[2];
        #pragma unroll
        for (int ks = 0; ks < 2; ++ks)
            af[ks] = *(const bf16x8*)(&zf[(g * 8 + (lm & 7)) * ZROW + ks * 32 + lg * 8]);

        #pragma unroll
        for (int il = 0; il < 4; ++il) {
            #pragma unroll
            for (int ks = 0; ks < 2; ++ks) {
                const int b = il + ks * 4;     // xr row base = i_loc + ks*4
                union { bf16x8 v; unsigned u[4]; } bf;
                asm("v_cvt_pk_bf16_f32 %0, %1, %2" : "=v"(bf.u[0]) : "v"(xr[0][b]),   "v"(xr[0][b+1]));
                asm("v_cvt_pk_bf16_f32 %0, %1, %2" : "=v"(bf.u[1]) : "v"(xr[0][b+2]), "v"(xr[0][b+3]));
                asm("v_cvt_pk_bf16_f32 %0, %1, %2" : "=v"(bf.u[2]) : "v"(xr[1][b]),   "v"(xr[1][b+1]));
                asm("v_cvt_pk_bf16_f32 %0, %1, %2" : "=v"(bf.u[3]) : "v"(xr[1][b+2]), "v"(xr[1][b+3]));
                acc[il] = __builtin_amdgcn_mfma_f32_16x16x32_bf16(af[ks], bf.v, acc[il], 0, 0, 0);
            }
        }
        __syncthreads();   // buf[(g+1)&1] staged AND buf[g&1] reads done
    }

    // ---- write U slab (plain stores; lg 0,1 hold the 8 valid q rows) ----
    if (lg < 2) {
        #pragma unroll
        for (int il = 0; il < 4; ++il) {
            const int iloc = rb + il;
            #pragma unroll
            for (int t = 0; t < 4; ++t)
                U[(iloc * 8 + lg * 4 + t) * UPITCH + jb + lm] = acc[il][t];
        }
    }
    __syncthreads();

    // ---- q-shift reduce + chunk accumulate ----
    if (tid < IH * MO) {
        const int il = tid / MO, j = tid - il * MO;
        float s = 0.f;
        #pragma unroll
        for (int q = 0; q < 8; ++q)
            s += U[(il * 8 + q) * UPITCH + j + q];
        atomicAdd(&out[(size_t)n * NOUT + (size_t)(i0 + il) * MO + j], s * (1.0f / 64.0f));
    }
}

extern "C" void kernel_launch(void* const* d_in, const int* in_sizes, int n_in,
                              void* d_out, int out_size, void* d_ws, size_t ws_size,
                              hipStream_t stream) {
    const float* z = (const float*)d_in[0];   // (16,256,8,8)
    const float* x = (const float*)d_in[1];   // (16,256,63,63)
    const float* w = (const float*)d_in[2];   // (1,256,1,1,1) -> 256 floats
    float* out = (float*)d_out;               // (16,1,56,56)

    // d_out re-poisoned each iteration; CSPLIT chunk blocks accumulate atomically.
    hipMemsetAsync(out, 0, (size_t)out_size * sizeof(float), stream);

    dim3 grid(NS, NBAND, CSPLIT);             // (16, 7, 8) = 896 blocks x 512 thr
    bhat_u<<<grid, 512, 0, stream>>>(z, x, w, out);
}

// Round 5
// 106.767 us; speedup vs baseline: 2.0702x; 1.4008x over previous
//
#include <hip/hip_runtime.h>
#include <math.h>

// out[n,0,i,j] = (1/64) * sum_{c,p,q} w[c]*sqrt(z[n,c,p,q]) * sqrt(x[n,c,i+p,j+q])
//   N=16, C=256, k=8, m=63, mo=56.
//
// U-formulation (round 4, verified): U[q][i][j] = sum_{c,p} Az[c][p*8+q]*sx[c][i+p][j]
// with K=(c,p), M=q, N=j; out[i][j] = (1/64) sum_q U[q][i][j+q]. No scatter.
//
// Round 5: round 4 was latency-bound in staging (load->sqrt->ds_write chains
// blocked each wave ~900cy per batch; all pipes <30%). Changes:
//   - stage RAW x via __builtin_amdgcn_global_load_lds (fire-and-forget, one
//     channel per wave, drained only at the end-of-iteration barrier) -> group
//     g+1's loads overlap group g's compute. sqrt moved to B-frag build.
//   - channel pitch 945->948 words (16B-divisible, lg-groups 8 banks apart):
//     xr ds_reads drop from 4-way to 2-way (free) bank aliasing.
//   - __builtin_amdgcn_sqrtf (raw v_sqrt_f32; bf16 rounding follows anyway).

#define NS 16
#define NC 256
#define MI 63
#define MO 56
#define NPIX (MI*MI)          // 3969
#define NOUT (MO*MO)          // 3136

#define IH 8                  // output rows per band
#define NBAND 7               // 7*8 = 56
#define CSPLIT 8              // channel chunks -> global atomic epilogue
#define NCH (NC/CSPLIT)       // 32 channels per block
#define G 8                   // channels per staging group (one per wave)
#define NG (NCH/G)            // 4 groups
#define XROWS (IH+7)          // 15 x-rows per band
#define XW (XROWS*MI)         // 945 valid words per channel
#define XCP 948               // padded channel pitch (fp32 words): 16B-divisible
#define ZROW 72               // zf padded row pitch (shorts)
#define UPITCH 66             // U row pitch (fp32)

typedef __attribute__((ext_vector_type(8))) short bf16x8;
typedef __attribute__((ext_vector_type(4))) float f32x4;
typedef __attribute__((address_space(3))) unsigned lds_u32;
typedef const __attribute__((address_space(1))) unsigned glb_u32;

static __device__ __forceinline__ short f2bf(float f) {
    union { float f; unsigned u; } v; v.f = f;
    return (short)((v.u + 0x7fffu + ((v.u >> 16) & 1u)) >> 16);
}

__global__ __launch_bounds__(512, 2)
void bhat_u(const float* __restrict__ z, const float* __restrict__ x,
            const float* __restrict__ w, float* __restrict__ out) {
    __shared__ float xs[2 * G * XCP];        // 60672 B: double-buffered RAW x tiles
    __shared__ short zf[NG * 8 * ZROW];      // 4608 B: A-frag-ready w*sqrt(z)
    float* U = xs;                           // q-slab aliases buf0 after the k-loop

    const int n    = blockIdx.x;
    const int band = blockIdx.y;
    const int c0   = blockIdx.z * NCH;
    const int tid  = threadIdx.x;
    const int i0   = band * IH;              // output row base; x rows i0..i0+14
    const int wave = tid >> 6, lane = tid & 63;

    // Async stage of group g into buf: wave w copies channel g*G+w (945 words,
    // 14 full + one 49-lane issue). LDS dest = uniform base + lane*4 (HW rule).
    auto stage = [&](int g, int buf) {
        const float* src = x + (size_t)(n * NC + c0 + g * G + wave) * NPIX + (size_t)i0 * MI;
        float* dst = &xs[buf * (G * XCP) + wave * XCP];
        #pragma unroll
        for (int it = 0; it < XW / 64; ++it)             // 14 issues
            __builtin_amdgcn_global_load_lds((glb_u32*)(src + it * 64 + lane),
                                             (lds_u32*)(dst + it * 64), 4, 0, 0);
        if (lane < XW - (XW / 64) * 64)                  // tail: 49 lanes
            __builtin_amdgcn_global_load_lds((glb_u32*)(src + (XW / 64) * 64 + lane),
                                             (lds_u32*)(dst + (XW / 64) * 64), 4, 0, 0);
    };

    stage(0, 0);   // fire-and-forget; latency hides under zf staging below

    // Stage A: zf[(g*8+q)*ZROW + k] = w*sqrt(z[c(k)][p(k)*8+q]),
    // k-order (within 32-k-step): c_local = (k&31)>>2, p = (k>>5)*4 + (k&3).
    {
        const float* zb = z + ((size_t)n * NC + c0) * 64;
        for (int idx = tid; idx < NG * 8 * 64; idx += 512) {
            int g = idx >> 9, rem = idx & 511;
            int q = rem >> 6, k = rem & 63;
            int cl = (k & 31) >> 2;
            int p  = ((k >> 5) << 2) + (k & 3);
            float v = w[c0 + g * G + cl] *
                      __builtin_amdgcn_sqrtf(zb[(size_t)(g * G + cl) * 64 + p * 8 + q]);
            zf[(g * 8 + q) * ZROW + k] = f2bf(v);
        }
    }

    asm volatile("s_waitcnt vmcnt(0)" ::: "memory");
    __syncthreads();

    const int wj = wave & 3, wh = wave >> 2;   // j-tile, row-half
    const int lm = lane & 15, lg = lane >> 4;
    const int jb = wj * 16;                    // B col base (0..48)
    const int rb = wh * 4;                     // first band row for this wave

    f32x4 acc[4];
    #pragma unroll
    for (int il = 0; il < 4; ++il) acc[il] = (f32x4){0.f, 0.f, 0.f, 0.f};

    for (int g = 0; g < NG; ++g) {
        if (g + 1 < NG) stage(g + 1, (g + 1) & 1);   // async; drained by barrier

        const float* xb = &xs[(g & 1) * (G * XCP)];
        // Register-cache + sqrt this lane's two x columns, rows rb..rb+10.
        // (col j=63 at wj=3 reads pad/garbage -> lands only in unread U col 63.)
        float xr[2][11];
        #pragma unroll
        for (int ci = 0; ci < 2; ++ci)
            #pragma unroll
            for (int r = 0; r < 11; ++r)
                xr[ci][r] = __builtin_amdgcn_sqrtf(
                    xb[(lg * 2 + ci) * XCP + (rb + r) * MI + jb + lm]);

        // A-frags: lane row q = lm&7 (rows 8-15 duplicate -> D rows 8-15 dup, unread).
        bf16x8 af[2];
        #pragma unroll
        for (int ks = 0; ks < 2; ++ks)
            af[ks] = *(const bf16x8*)(&zf[(g * 8 + (lm & 7)) * ZROW + ks * 32 + lg * 8]);

        #pragma unroll
        for (int il = 0; il < 4; ++il) {
            #pragma unroll
            for (int ks = 0; ks < 2; ++ks) {
                const int b = il + ks * 4;     // xr row base = i_loc + ks*4
                union { bf16x8 v; unsigned u[4]; } bf;
                asm("v_cvt_pk_bf16_f32 %0, %1, %2" : "=v"(bf.u[0]) : "v"(xr[0][b]),   "v"(xr[0][b+1]));
                asm("v_cvt_pk_bf16_f32 %0, %1, %2" : "=v"(bf.u[1]) : "v"(xr[0][b+2]), "v"(xr[0][b+3]));
                asm("v_cvt_pk_bf16_f32 %0, %1, %2" : "=v"(bf.u[2]) : "v"(xr[1][b]),   "v"(xr[1][b+1]));
                asm("v_cvt_pk_bf16_f32 %0, %1, %2" : "=v"(bf.u[3]) : "v"(xr[1][b+2]), "v"(xr[1][b+3]));
                acc[il] = __builtin_amdgcn_mfma_f32_16x16x32_bf16(af[ks], bf.v, acc[il], 0, 0, 0);
            }
        }
        asm volatile("s_waitcnt vmcnt(0)" ::: "memory");  // my stage issues done
        __syncthreads();   // all waves: buf[(g+1)&1] staged AND buf[g&1] reads done
    }

    // ---- write U slab (plain stores; lg 0,1 hold the 8 valid q rows) ----
    if (lg < 2) {
        #pragma unroll
        for (int il = 0; il < 4; ++il) {
            const int iloc = rb + il;
            #pragma unroll
            for (int t = 0; t < 4; ++t)
                U[(iloc * 8 + lg * 4 + t) * UPITCH + jb + lm] = acc[il][t];
        }
    }
    __syncthreads();

    // ---- q-shift reduce + chunk accumulate ----
    if (tid < IH * MO) {
        const int il = tid / MO, j = tid - il * MO;
        float s = 0.f;
        #pragma unroll
        for (int q = 0; q < 8; ++q)
            s += U[(il * 8 + q) * UPITCH + j + q];
        atomicAdd(&out[(size_t)n * NOUT + (size_t)(i0 + il) * MO + j], s * (1.0f / 64.0f));
    }
}

extern "C" void kernel_launch(void* const* d_in, const int* in_sizes, int n_in,
                              void* d_out, int out_size, void* d_ws, size_t ws_size,
                              hipStream_t stream) {
    const float* z = (const float*)d_in[0];   // (16,256,8,8)
    const float* x = (const float*)d_in[1];   // (16,256,63,63)
    const float* w = (const float*)d_in[2];   // (1,256,1,1,1) -> 256 floats
    float* out = (float*)d_out;               // (16,1,56,56)

    // d_out re-poisoned each iteration; CSPLIT chunk blocks accumulate atomically.
    hipMemsetAsync(out, 0, (size_t)out_size * sizeof(float), stream);

    dim3 grid(NS, NBAND, CSPLIT);             // (16, 7, 8) = 896 blocks x 512 thr
    bhat_u<<<grid, 512, 0, stream>>>(z, x, w, out);
}

// Round 6
// 103.341 us; speedup vs baseline: 2.1388x; 1.0332x over previous
//
#include <hip/hip_runtime.h>
#include <math.h>

// out[n,0,i,j] = (1/64) * sum_{c,p,q} w[c]*sqrt(z[n,c,p,q]) * sqrt(x[n,c,i+p,j+q])
//   N=16, C=256, k=8, m=63, mo=56.
//
// U-formulation (verified rounds 4/5): U[q][i][j] = sum_{c,p} Az[c][p*8+q]*sx[c][i+p][j]
// with K=(c,p), M=q, N=j; out[i][j] = (1/64) sum_q U[q][i][j+q]. No scatter.
//
// Round 6: round 5's kernel (~35-40us, backed out of dur) was scheduling-bound:
//   launch_bounds(512,2) = 2 waves/EU = 1 block/CU, grid 896 -> ~3.5 sequential
//   block rounds per CU with only 8 waves/CU of latency hiding.
// Changes:
//   - CSPLIT 8->4 (64ch/block, NG=8 iters), grid 448 blocks; launch_bounds(512,4)
//     -> 2 blocks/CU -> ALL blocks co-resident, single round; kernel ~ 1 block's latency.
//   - zf (A-matrix) becomes per-group double-buffer (2.3KB) staged per-iteration,
//     T14-split (z loads issued before compute, cvt+ds_write after), so total LDS
//     = 62976 B fits the 64KB static limit. g-loop fully unrolled (static indices).

#define NS 16
#define NC 256
#define MI 63
#define MO 56
#define NPIX (MI*MI)          // 3969
#define NOUT (MO*MO)          // 3136

#define IH 8                  // output rows per band
#define NBAND 7               // 7*8 = 56
#define CSPLIT 4              // channel chunks -> global atomic epilogue
#define NCH (NC/CSPLIT)       // 64 channels per block
#define G 8                   // channels per staging group (one per wave)
#define NG (NCH/G)            // 8 groups
#define XROWS (IH+7)          // 15 x-rows per band
#define XW (XROWS*MI)         // 945 valid words per channel
#define XCP 948               // padded channel pitch (fp32 words): lg-groups 8 banks apart
#define ZROW 72               // zf row pitch (shorts): q-rows rotate 4 banks, 16B-aligned
#define UPITCH 66             // U row pitch (fp32)

typedef __attribute__((ext_vector_type(8))) short bf16x8;
typedef __attribute__((ext_vector_type(4))) float f32x4;
typedef __attribute__((address_space(3))) unsigned lds_u32;
typedef const __attribute__((address_space(1))) unsigned glb_u32;

static __device__ __forceinline__ short f2bf(float f) {
    union { float f; unsigned u; } v; v.f = f;
    return (short)((v.u + 0x7fffu + ((v.u >> 16) & 1u)) >> 16);
}

__global__ __launch_bounds__(512, 4)
void bhat_u(const float* __restrict__ z, const float* __restrict__ x,
            const float* __restrict__ w, float* __restrict__ out) {
    __shared__ float xs[2 * G * XCP];        // 60672 B: double-buffered RAW x tiles
    __shared__ short zf[2 * 8 * ZROW];       //  2304 B: per-group dbuf A-frags
    float* U = xs;                           // q-slab aliases buf0 after the k-loop

    const int n    = blockIdx.x;
    const int band = blockIdx.y;
    const int c0   = blockIdx.z * NCH;
    const int tid  = threadIdx.x;
    const int i0   = band * IH;              // output row base; x rows i0..i0+14
    const int wave = tid >> 6, lane = tid & 63;

    // ---- per-thread A-staging constants: tid -> (q, k) -> (cl, p) ----
    const int zq = tid >> 6, zk = tid & 63;
    const int zcl = (zk & 31) >> 2;
    const int zp  = ((zk >> 5) << 2) + (zk & 3);
    const float* zptr = z + ((size_t)n * NC + c0 + zcl) * 64 + zp * 8 + zq;
    float wv[NG];
    #pragma unroll
    for (int g = 0; g < NG; ++g) wv[g] = w[c0 + g * G + zcl];

    // Async x stage of group g into buf: wave w copies channel g*G+w (945 words).
    auto stage = [&](int g, int buf) {
        const float* src = x + (size_t)(n * NC + c0 + g * G + wave) * NPIX + (size_t)i0 * MI;
        float* dst = &xs[buf * (G * XCP) + wave * XCP];
        #pragma unroll
        for (int it = 0; it < XW / 64; ++it)             // 14 issues
            __builtin_amdgcn_global_load_lds((glb_u32*)(src + it * 64 + lane),
                                             (lds_u32*)(dst + it * 64), 4, 0, 0);
        if (lane < XW - (XW / 64) * 64)                  // tail: 49 lanes
            __builtin_amdgcn_global_load_lds((glb_u32*)(src + (XW / 64) * 64 + lane),
                                             (lds_u32*)(dst + (XW / 64) * 64), 4, 0, 0);
    };

    // ---- prologue: stage group 0 (x async + z reg) ----
    stage(0, 0);
    {
        float zv = *zptr;
        zf[zq * ZROW + zk] = f2bf(wv[0] * __builtin_amdgcn_sqrtf(zv));
    }
    asm volatile("s_waitcnt vmcnt(0)" ::: "memory");
    __syncthreads();

    const int wj = wave & 3, wh = wave >> 2;   // j-tile, row-half
    const int lm = lane & 15, lg = lane >> 4;
    const int jb = wj * 16;                    // B col base (0..48)
    const int rb = wh * 4;                     // first band row for this wave

    f32x4 acc[4];
    #pragma unroll
    for (int il = 0; il < 4; ++il) acc[il] = (f32x4){0.f, 0.f, 0.f, 0.f};

    #pragma unroll
    for (int g = 0; g < NG; ++g) {
        // Issue next group's staging loads BEFORE compute (T14 issue-early).
        float znext = 0.f;
        if (g + 1 < NG) {
            stage(g + 1, (g + 1) & 1);
            znext = zptr[(g + 1) * G * 64];    // z for group g+1 (write deferred)
        }

        const float* xb = &xs[(g & 1) * (G * XCP)];
        // Register-cache + sqrt this lane's two x columns, rows rb..rb+10.
        // (col j=63 at wj=3 reads pad/garbage -> lands only in unread U col 63.)
        float xr[2][11];
        #pragma unroll
        for (int ci = 0; ci < 2; ++ci)
            #pragma unroll
            for (int r = 0; r < 11; ++r)
                xr[ci][r] = __builtin_amdgcn_sqrtf(
                    xb[(lg * 2 + ci) * XCP + (rb + r) * MI + jb + lm]);

        // A-frags: lane row q = lm&7 (rows 8-15 duplicate -> D rows 8-15 dup, unread).
        bf16x8 af[2];
        #pragma unroll
        for (int ks = 0; ks < 2; ++ks)
            af[ks] = *(const bf16x8*)(&zf[(g & 1) * 8 * ZROW + (lm & 7) * ZROW + ks * 32 + lg * 8]);

        #pragma unroll
        for (int il = 0; il < 4; ++il) {
            #pragma unroll
            for (int ks = 0; ks < 2; ++ks) {
                const int b = il + ks * 4;     // xr row base = i_loc + ks*4
                union { bf16x8 v; unsigned u[4]; } bf;
                asm("v_cvt_pk_bf16_f32 %0, %1, %2" : "=v"(bf.u[0]) : "v"(xr[0][b]),   "v"(xr[0][b+1]));
                asm("v_cvt_pk_bf16_f32 %0, %1, %2" : "=v"(bf.u[1]) : "v"(xr[0][b+2]), "v"(xr[0][b+3]));
                asm("v_cvt_pk_bf16_f32 %0, %1, %2" : "=v"(bf.u[2]) : "v"(xr[1][b]),   "v"(xr[1][b+1]));
                asm("v_cvt_pk_bf16_f32 %0, %1, %2" : "=v"(bf.u[3]) : "v"(xr[1][b+2]), "v"(xr[1][b+3]));
                acc[il] = __builtin_amdgcn_mfma_f32_16x16x32_bf16(af[ks], bf.v, acc[il], 0, 0, 0);
            }
        }

        // Deferred A-write for group g+1 (T14 write-late; same barrier drains it).
        if (g + 1 < NG)
            zf[((g + 1) & 1) * 8 * ZROW + zq * ZROW + zk] =
                f2bf(wv[g + 1] * __builtin_amdgcn_sqrtf(znext));

        asm volatile("s_waitcnt vmcnt(0)" ::: "memory");  // my stage issues done
        __syncthreads();   // all waves: next buf staged AND current buf reads done
    }

    // ---- write U slab (plain stores; lg 0,1 hold the 8 valid q rows) ----
    if (lg < 2) {
        #pragma unroll
        for (int il = 0; il < 4; ++il) {
            const int iloc = rb + il;
            #pragma unroll
            for (int t = 0; t < 4; ++t)
                U[(iloc * 8 + lg * 4 + t) * UPITCH + jb + lm] = acc[il][t];
        }
    }
    __syncthreads();

    // ---- q-shift reduce + chunk accumulate ----
    if (tid < IH * MO) {
        const int il = tid / MO, j = tid - il * MO;
        float s = 0.f;
        #pragma unroll
        for (int q = 0; q < 8; ++q)
            s += U[(il * 8 + q) * UPITCH + j + q];
        atomicAdd(&out[(size_t)n * NOUT + (size_t)(i0 + il) * MO + j], s * (1.0f / 64.0f));
    }
}

extern "C" void kernel_launch(void* const* d_in, const int* in_sizes, int n_in,
                              void* d_out, int out_size, void* d_ws, size_t ws_size,
                              hipStream_t stream) {
    const float* z = (const float*)d_in[0];   // (16,256,8,8)
    const float* x = (const float*)d_in[1];   // (16,256,63,63)
    const float* w = (const float*)d_in[2];   // (1,256,1,1,1) -> 256 floats
    float* out = (float*)d_out;               // (16,1,56,56)

    // d_out re-poisoned each iteration; CSPLIT chunk blocks accumulate atomically.
    hipMemsetAsync(out, 0, (size_t)out_size * sizeof(float), stream);

    dim3 grid(NS, NBAND, CSPLIT);             // (16, 7, 4) = 448 blocks x 512 thr
    bhat_u<<<grid, 512, 0, stream>>>(z, x, w, out);
}

// Round 7
// 103.051 us; speedup vs baseline: 2.1448x; 1.0028x over previous
//
#include <hip/hip_runtime.h>
#include <math.h>

// out[n,0,i,j] = (1/64) * sum_{c,p,q} w[c]*sqrt(z[n,c,p,q]) * sqrt(x[n,c,i+p,j+q])
//   N=16, C=256, k=8, m=63, mo=56.
//
// U-formulation (verified r4-r6): U[q][i][j] = sum_{c,p} Az[c][p*8+q]*sx[c][i+p][j],
// K=(c,p), M=q, N=j; out[i][j] = (1/64) sum_q U[q][i][j+q]. No scatter.
//
// Round 7: r6 kernel = 23.7us but all pipes <25% (stall-bound). Changes:
//   - width-16 global_load_lds staging: 15 width-4 issues -> 4 width-16 issues
//     per wave per iter (4x fewer DMA ops; m97's biggest single lever). 16B
//     alignment via per-channel start shift (c&3 words), compensated at read
//     time by the compile-time constant (lg*2+ci)&3 -> banks stay 2-way free.
//   - XCD swizzle: all 28 blocks of one sample (4.06MB ~= one XCD L2) on one
//     XCD, band-adjacent blocks (47% x-row overlap) adjacent.

#define NS 16
#define NC 256
#define MI 63
#define MO 56
#define NPIX (MI*MI)          // 3969
#define NOUT (MO*MO)          // 3136

#define IH 8                  // output rows per band
#define NBAND 7               // 7*8 = 56
#define CSPLIT 4              // channel chunks -> global atomic epilogue
#define NCH (NC/CSPLIT)       // 64 channels per block
#define G 8                   // channels per staging group (one per wave)
#define NG (NCH/G)            // 8 groups
#define XROWS (IH+7)          // 15 x-rows per band
#define XW (XROWS*MI)         // 945 valid words per channel
#define XCP 948               // padded channel pitch (fp32 words) = 237 float4
#define ZROW 72               // zf row pitch (shorts)
#define UPITCH 66             // U row pitch (fp32)

typedef __attribute__((ext_vector_type(8))) short bf16x8;
typedef __attribute__((ext_vector_type(4))) float f32x4;
typedef __attribute__((address_space(3))) unsigned lds_u32;
typedef const __attribute__((address_space(1))) unsigned glb_u32;

static __device__ __forceinline__ short f2bf(float f) {
    union { float f; unsigned u; } v; v.f = f;
    return (short)((v.u + 0x7fffu + ((v.u >> 16) & 1u)) >> 16);
}

__global__ __launch_bounds__(512, 4)
void bhat_u(const float* __restrict__ z, const float* __restrict__ x,
            const float* __restrict__ w, float* __restrict__ out) {
    __shared__ float xs[2 * G * XCP + 4];    // 60688 B: dbuf RAW x tiles (+pad reads)
    __shared__ short zf[2 * 8 * ZROW];       //  2304 B: per-group dbuf A-frags
    float* U = xs;                           // q-slab aliases buf0 after the k-loop

    // XCD swizzle: HW maps block b -> XCD b&7. Put sample n on XCD n&7, its 28
    // (chunk,band) blocks consecutive (band fastest: adjacent bands share 7/15 rows).
    const int bid  = blockIdx.x;
    const int xcd  = bid & 7, rest = bid >> 3;
    const int nhi  = rest / 28, rr = rest - nhi * 28;
    const int n    = nhi * 8 + xcd;
    const int band = rr % 7;
    const int c0   = (rr / 7) * NCH;

    const int tid  = threadIdx.x;
    const int i0   = band * IH;              // output row base; x rows i0..i0+14
    const int wave = tid >> 6, lane = tid & 63;

    // ---- per-thread A-staging constants: tid -> (q, k) -> (cl, p) ----
    const int zq = tid >> 6, zk = tid & 63;
    const int zcl = (zk & 31) >> 2;
    const int zp  = ((zk >> 5) << 2) + (zk & 3);
    const float* zptr = z + ((size_t)n * NC + c0 + zcl) * 64 + zp * 8 + zq;
    float wv[NG];
    #pragma unroll
    for (int g = 0; g < NG; ++g) wv[g] = w[c0 + g * G + zcl];

    // Async x stage of group g into buf: wave stages channel g*G+wave as exactly
    // 237 float4 (948 words) from the 16B-aligned start (start - (ch&3) words).
    auto stage = [&](int g, int buf) {
        const int ch = c0 + g * G + wave;
        const float* src = x + (size_t)(n * NC + ch) * NPIX + (size_t)i0 * MI - (ch & 3);
        float* dst = &xs[buf * (G * XCP) + wave * XCP];
        #pragma unroll
        for (int it = 0; it < 3; ++it)                   // 3 full 64-lane issues
            __builtin_amdgcn_global_load_lds((glb_u32*)(src + it * 256 + lane * 4),
                                             (lds_u32*)(dst + it * 256), 16, 0, 0);
        if (lane < 45)                                   // tail: 45 lanes x float4
            __builtin_amdgcn_global_load_lds((glb_u32*)(src + 768 + lane * 4),
                                             (lds_u32*)(dst + 768), 16, 0, 0);
    };

    // ---- prologue: stage group 0 (x async + z reg) ----
    stage(0, 0);
    {
        float zv = *zptr;
        zf[zq * ZROW + zk] = f2bf(wv[0] * __builtin_amdgcn_sqrtf(zv));
    }
    asm volatile("s_waitcnt vmcnt(0)" ::: "memory");
    __syncthreads();

    const int wj = wave & 3, wh = wave >> 2;   // j-tile, row-half
    const int lm = lane & 15, lg = lane >> 4;
    const int jb = wj * 16;                    // B col base (0..48)
    const int rb = wh * 4;                     // first band row for this wave

    f32x4 acc[4];
    #pragma unroll
    for (int il = 0; il < 4; ++il) acc[il] = (f32x4){0.f, 0.f, 0.f, 0.f};

    #pragma unroll
    for (int g = 0; g < NG; ++g) {
        // Issue next group's staging loads BEFORE compute (T14 issue-early).
        float znext = 0.f;
        if (g + 1 < NG) {
            stage(g + 1, (g + 1) & 1);
            znext = zptr[(g + 1) * G * 64];    // z for group g+1 (write deferred)
        }

        const float* xb = &xs[(g & 1) * (G * XCP)];
        // Register-cache + sqrt this lane's two x columns, rows rb..rb+10.
        // Channel ci's data sits shifted by sh = (lg*2+ci)&3 (alignment shift);
        // banks: lm(16) + 8*lg + sh -> lg0/lg2 and lg1/lg3 cover disjoint halves
        // -> still exactly 2 lanes/bank (free). Col j=63 at wj=3 reads pad ->
        // lands only in unread U col 63.
        float xr[2][11];
        #pragma unroll
        for (int ci = 0; ci < 2; ++ci) {
            const int sh = (lg * 2 + ci) & 3;
            #pragma unroll
            for (int r = 0; r < 11; ++r)
                xr[ci][r] = __builtin_amdgcn_sqrtf(
                    xb[(lg * 2 + ci) * XCP + sh + (rb + r) * MI + jb + lm]);
        }

        // A-frags: lane row q = lm&7 (rows 8-15 duplicate -> D rows 8-15 dup, unread).
        bf16x8 af[2];
        #pragma unroll
        for (int ks = 0; ks < 2; ++ks)
            af[ks] = *(const bf16x8*)(&zf[(g & 1) * 8 * ZROW + (lm & 7) * ZROW + ks * 32 + lg * 8]);

        #pragma unroll
        for (int il = 0; il < 4; ++il) {
            #pragma unroll
            for (int ks = 0; ks < 2; ++ks) {
                const int b = il + ks * 4;     // xr row base = i_loc + ks*4
                union { bf16x8 v; unsigned u[4]; } bf;
                asm("v_cvt_pk_bf16_f32 %0, %1, %2" : "=v"(bf.u[0]) : "v"(xr[0][b]),   "v"(xr[0][b+1]));
                asm("v_cvt_pk_bf16_f32 %0, %1, %2" : "=v"(bf.u[1]) : "v"(xr[0][b+2]), "v"(xr[0][b+3]));
                asm("v_cvt_pk_bf16_f32 %0, %1, %2" : "=v"(bf.u[2]) : "v"(xr[1][b]),   "v"(xr[1][b+1]));
                asm("v_cvt_pk_bf16_f32 %0, %1, %2" : "=v"(bf.u[3]) : "v"(xr[1][b+2]), "v"(xr[1][b+3]));
                acc[il] = __builtin_amdgcn_mfma_f32_16x16x32_bf16(af[ks], bf.v, acc[il], 0, 0, 0);
            }
        }

        // Deferred A-write for group g+1 (T14 write-late; same barrier drains it).
        if (g + 1 < NG)
            zf[((g + 1) & 1) * 8 * ZROW + zq * ZROW + zk] =
                f2bf(wv[g + 1] * __builtin_amdgcn_sqrtf(znext));

        asm volatile("s_waitcnt vmcnt(0)" ::: "memory");  // my stage issues done
        __syncthreads();   // all waves: next buf staged AND current buf reads done
    }

    // ---- write U slab (plain stores; lg 0,1 hold the 8 valid q rows) ----
    if (lg < 2) {
        #pragma unroll
        for (int il = 0; il < 4; ++il) {
            const int iloc = rb + il;
            #pragma unroll
            for (int t = 0; t < 4; ++t)
                U[(iloc * 8 + lg * 4 + t) * UPITCH + jb + lm] = acc[il][t];
        }
    }
    __syncthreads();

    // ---- q-shift reduce + chunk accumulate ----
    if (tid < IH * MO) {
        const int il = tid / MO, j = tid - il * MO;
        float s = 0.f;
        #pragma unroll
        for (int q = 0; q < 8; ++q)
            s += U[(il * 8 + q) * UPITCH + j + q];
        atomicAdd(&out[(size_t)n * NOUT + (size_t)(i0 + il) * MO + j], s * (1.0f / 64.0f));
    }
}

extern "C" void kernel_launch(void* const* d_in, const int* in_sizes, int n_in,
                              void* d_out, int out_size, void* d_ws, size_t ws_size,
                              hipStream_t stream) {
    const float* z = (const float*)d_in[0];   // (16,256,8,8)
    const float* x = (const float*)d_in[1];   // (16,256,63,63)
    const float* w = (const float*)d_in[2];   // (1,256,1,1,1) -> 256 floats
    float* out = (float*)d_out;               // (16,1,56,56)

    // d_out re-poisoned each iteration; CSPLIT chunk blocks accumulate atomically.
    hipMemsetAsync(out, 0, (size_t)out_size * sizeof(float), stream);

    bhat_u<<<dim3(NS * NBAND * CSPLIT), 512, 0, stream>>>(z, x, w, out);
}